// Round 6
// baseline (98.462 us; speedup 1.0000x reference)
//
#include <hip/hip_runtime.h>

typedef float f32x4 __attribute__((ext_vector_type(4)));
typedef float f32x2 __attribute__((ext_vector_type(2)));

#define NSEAS 3
#define NRES  2
#define NCOMP 5
#define KNB   8
#define TWO_PI_F 6.28318530717958647692f
#define SPB  100         // stations per block; 1000 * 100 = 100000 exactly
#define BSIG 512         // 8 waves: two 256-thread halves, even/odd stations

static __device__ __forceinline__ f32x2 bc2(float x) {
    f32x2 r; r.x = x; r.y = x; return r;
}

// Fused kernel, occupancy-oriented variant.
// Phase 1a: lane tid<nst computes smoothed 12 coeffs for station stBeg+tid -> LDS.
// Phase 1b: every streaming thread builds its sin/cos time basis in registers.
// Phase 2:  half h = tid>>8 handles stations s = h, h+2, h+4 ... (x2 unrolled),
//           packed-f32 FMAs, one f32x4 store per station per thread.
// __launch_bounds__(512,4): cap VGPR <= 128 -> 4 waves/SIMD (2 blocks/CU).
__global__ __launch_bounds__(BSIG, 4) void fused_insar_kernel(
    const float* __restrict__ time_vector,
    const float* __restrict__ constant_offset,
    const float* __restrict__ linear_trend,
    const float* __restrict__ seas_amp,
    const float* __restrict__ seas_phase,
    const float* __restrict__ res_amp,
    const float* __restrict__ res_phase,
    const float* __restrict__ res_periods,
    const float* __restrict__ periods,
    const int*   __restrict__ nb_idx,
    const float* __restrict__ nb_w,
    float* __restrict__ out,
    int N, int T)
{
    __shared__ __align__(16) float sp[SPB * 12];

    const int tid   = threadIdx.x;
    const int stBeg = blockIdx.x * SPB;
    const int nst   = min(SPB, N - stBeg);   // 100 for all blocks here

    // ---------------- Phase 1a: smoothing -> LDS (one lane per station) ---
    if (tid < nst) {
        const int st = stBeg + tid;
        const float S = 0.12f, OMS = 1.0f - 0.12f;

        const int4*  ip = reinterpret_cast<const int4*>(nb_idx + st * KNB);
        const f32x4* wp = reinterpret_cast<const f32x4*>(nb_w + st * KNB);
        int4  i0 = ip[0], i1 = ip[1];
        f32x4 w0 = wp[0], w1 = wp[1];
        int   idx[KNB] = {i0.x, i0.y, i0.z, i0.w, i1.x, i1.y, i1.z, i1.w};
        float w[KNB]   = {w0.x, w0.y, w0.z, w0.w, w1.x, w1.y, w1.z, w1.w};

        float accA[NSEAS]  = {0.f, 0.f, 0.f};
        float accRe[NSEAS] = {0.f, 0.f, 0.f};
        float accIm[NSEAS] = {0.f, 0.f, 0.f};

        #pragma unroll
        for (int k = 0; k < KNB; ++k) {
            int nb = idx[k];
            #pragma unroll
            for (int i = 0; i < NSEAS; ++i) {
                float a = seas_amp[nb * NSEAS + i];
                float p = seas_phase[nb * NSEAS + i];
                float spn, cpn;
                __sincosf(p, &spn, &cpn);
                accA[i]  = fmaf(w[k], a,   accA[i]);
                accRe[i] = fmaf(w[k], cpn, accRe[i]);
                accIm[i] = fmaf(w[k], spn, accIm[i]);
            }
        }

        float outp[12];
        outp[0] = constant_offset[st];
        outp[1] = linear_trend[st];

        #pragma unroll
        for (int i = 0; i < NSEAS; ++i) {
            float smA = OMS * seas_amp[st * NSEAS + i] + S * accA[i];
            float spn, cpn;
            __sincosf(seas_phase[st * NSEAS + i], &spn, &cpn);
            float re = OMS * cpn + S * accRe[i];
            float im = OMS * spn + S * accIm[i];
            // cos(atan2(im,re)) = re/r ; sin(atan2(im,re)) = im/r
            float r   = sqrtf(re * re + im * im);
            float inv = smA / fmaxf(r, 1e-30f);
            outp[2 + 2 * i] = re * inv;
            outp[3 + 2 * i] = im * inv;
        }

        #pragma unroll
        for (int i = 0; i < NRES; ++i) {
            float a = res_amp[st * NRES + i];
            float spn, cpn;
            __sincosf(res_phase[st * NRES + i], &spn, &cpn);
            outp[2 + 2 * (NSEAS + i)] = a * cpn;
            outp[3 + 2 * (NSEAS + i)] = a * spn;
        }

        f32x4* po = reinterpret_cast<f32x4*>(sp + tid * 12);
        po[0] = f32x4{outp[0], outp[1], outp[2],  outp[3]};
        po[1] = f32x4{outp[4], outp[5], outp[6],  outp[7]};
        po[2] = f32x4{outp[8], outp[9], outp[10], outp[11]};
    }

    // ---------------- Phase 1b: time basis in registers ----------------
    const int tid8 = tid & 255;
    const int half = tid >> 8;        // 0: even stations, 1: odd stations
    const int t0   = tid8 * 4;
    const bool active = (t0 + 3) < T; // T=1000 -> tid8 0..249

    f32x2 tv2[2];
    f32x2 sT2[NCOMP][2], cT2[NCOMP][2];
    if (active) {
        f32x4 t4 = *reinterpret_cast<const f32x4*>(time_vector + t0);
        tv2[0].x = t4.x; tv2[0].y = t4.y;
        tv2[1].x = t4.z; tv2[1].y = t4.w;
        #pragma unroll
        for (int c = 0; c < NCOMP; ++c) {
            float f = (c < NSEAS) ? (1.0f / periods[c])
                                  : (1.0f / res_periods[c - NSEAS]);
            float wc = TWO_PI_F * f;
            float s0, c0, s1, c1, s2, c2, s3, c3;
            __sincosf(wc * t4.x, &s0, &c0);
            __sincosf(wc * t4.y, &s1, &c1);
            __sincosf(wc * t4.z, &s2, &c2);
            __sincosf(wc * t4.w, &s3, &c3);
            sT2[c][0].x = s0; sT2[c][0].y = s1;
            sT2[c][1].x = s2; sT2[c][1].y = s3;
            cT2[c][0].x = c0; cT2[c][0].y = c1;
            cT2[c][1].x = c2; cT2[c][1].y = c3;
        }
    }

    __syncthreads();

    // ---------------- Phase 2: stream this half's stations ----------------
    // Compute + store one station from 3 coeff vectors.
    auto dost = [&](int s, f32x4 P0, f32x4 P1, f32x4 P2) {
        f32x2 of = bc2(P0.x), tr = bc2(P0.y);
        f32x2 a0 = __builtin_elementwise_fma(tr, tv2[0], of);
        f32x2 a1 = __builtin_elementwise_fma(tr, tv2[1], of);
        a0 = __builtin_elementwise_fma(bc2(P0.z), sT2[0][0], a0);
        a1 = __builtin_elementwise_fma(bc2(P0.z), sT2[0][1], a1);
        a0 = __builtin_elementwise_fma(bc2(P0.w), cT2[0][0], a0);
        a1 = __builtin_elementwise_fma(bc2(P0.w), cT2[0][1], a1);
        a0 = __builtin_elementwise_fma(bc2(P1.x), sT2[1][0], a0);
        a1 = __builtin_elementwise_fma(bc2(P1.x), sT2[1][1], a1);
        a0 = __builtin_elementwise_fma(bc2(P1.y), cT2[1][0], a0);
        a1 = __builtin_elementwise_fma(bc2(P1.y), cT2[1][1], a1);
        a0 = __builtin_elementwise_fma(bc2(P1.z), sT2[2][0], a0);
        a1 = __builtin_elementwise_fma(bc2(P1.z), sT2[2][1], a1);
        a0 = __builtin_elementwise_fma(bc2(P1.w), cT2[2][0], a0);
        a1 = __builtin_elementwise_fma(bc2(P1.w), cT2[2][1], a1);
        a0 = __builtin_elementwise_fma(bc2(P2.x), sT2[3][0], a0);
        a1 = __builtin_elementwise_fma(bc2(P2.x), sT2[3][1], a1);
        a0 = __builtin_elementwise_fma(bc2(P2.y), cT2[3][0], a0);
        a1 = __builtin_elementwise_fma(bc2(P2.y), cT2[3][1], a1);
        a0 = __builtin_elementwise_fma(bc2(P2.z), sT2[4][0], a0);
        a1 = __builtin_elementwise_fma(bc2(P2.z), sT2[4][1], a1);
        a0 = __builtin_elementwise_fma(bc2(P2.w), cT2[4][0], a0);
        a1 = __builtin_elementwise_fma(bc2(P2.w), cT2[4][1], a1);
        f32x4 o; o.x = a0.x; o.y = a0.y; o.z = a1.x; o.w = a1.y;
        *reinterpret_cast<f32x4*>(out + (size_t)(stBeg + s) * T + t0) = o;
    };

    const f32x4* spv = reinterpret_cast<const f32x4*>(sp);

    if (active) {
        int s = half;
        // x2-unrolled: two stations' coeff reads issued before both computes.
        for (; s + 2 < nst; s += 4) {
            f32x4 A0 = spv[3 * s],       A1 = spv[3 * s + 1],       A2 = spv[3 * s + 2];
            f32x4 B0 = spv[3 * (s + 2)], B1 = spv[3 * (s + 2) + 1], B2 = spv[3 * (s + 2) + 2];
            dost(s, A0, A1, A2);
            dost(s + 2, B0, B1, B2);
        }
        for (; s < nst; s += 2) {
            dost(s, spv[3 * s], spv[3 * s + 1], spv[3 * s + 2]);
        }
    } else if (t0 < T) {
        // Generic T-tail (unused for T=1000): scalar path.
        for (int s = half; s < nst; s += 2) {
            const f32x4* pv = spv + 3 * s;
            f32x4 P0 = pv[0], P1 = pv[1], P2 = pv[2];
            float off = P0.x, trend = P0.y;
            float cs[NCOMP] = {P0.z, P1.x, P1.z, P2.x, P2.z};
            float cc[NCOMP] = {P0.w, P1.y, P1.w, P2.y, P2.w};
            for (int j = 0; j < 4 && t0 + j < T; ++j) {
                int t = t0 + j;
                float tt = time_vector[t];
                float acc = fmaf(trend, tt, off);
                for (int i = 0; i < NCOMP; ++i) {
                    float f = (i < NSEAS) ? (1.0f / periods[i])
                                          : (1.0f / res_periods[i - NSEAS]);
                    float sv, cv;
                    __sincosf(TWO_PI_F * f * tt, &sv, &cv);
                    acc = fmaf(cs[i], sv, acc);
                    acc = fmaf(cc[i], cv, acc);
                }
                out[(size_t)(stBeg + s) * T + t] = acc;
            }
        }
    }
}

extern "C" void kernel_launch(void* const* d_in, const int* in_sizes, int n_in,
                              void* d_out, int out_size, void* d_ws, size_t ws_size,
                              hipStream_t stream) {
    const float* time_vector     = (const float*)d_in[0];
    const float* constant_offset = (const float*)d_in[1];
    const float* linear_trend    = (const float*)d_in[2];
    const float* seas_amp        = (const float*)d_in[3];
    const float* seas_phase      = (const float*)d_in[4];
    const float* res_amp         = (const float*)d_in[5];
    const float* res_phase       = (const float*)d_in[6];
    const float* res_periods     = (const float*)d_in[7];
    const float* periods         = (const float*)d_in[8];
    const int*   nb_idx          = (const int*)d_in[9];
    const float* nb_w            = (const float*)d_in[10];

    int T = in_sizes[0];
    int N = in_sizes[1];

    float* out = (float*)d_out;

    int grid = (N + SPB - 1) / SPB;   // 1000 blocks for N=100000
    fused_insar_kernel<<<grid, BSIG, 0, stream>>>(
        time_vector, constant_offset, linear_trend,
        seas_amp, seas_phase, res_amp, res_phase,
        res_periods, periods, nb_idx, nb_w,
        out, N, T);
}